// Round 1
// baseline (261.560 us; speedup 1.0000x reference)
//
#include <hip/hip_runtime.h>
#include <hip/hip_fp16.h>
#include <type_traits>

#define NEG_SLOPE 0.2f
#define BKT_SHIFT 8
#define BKT_SIZE (1 << BKT_SHIFT)     // 256 dst nodes per bucket
#define BKT_CAP 12288                 // arena slots/bucket (mean 4096; overflow ~impossible)
#define P1_EPT 16                     // edges per thread in partition pass

typedef __attribute__((ext_vector_type(8))) short short8;
typedef __attribute__((ext_vector_type(4))) float float4v;

__device__ inline int rfl_i(int v) { return __builtin_amdgcn_readfirstlane(v); }

// round-to-nearest-even fp32 -> bf16
__device__ inline unsigned short f2bf(float f) {
    unsigned u = __float_as_uint(f);
    unsigned r = u + 0x7FFFu + ((u >> 16) & 1u);
    return (unsigned short)(r >> 16);
}
__device__ inline float bf2f(unsigned short b) {
    return __uint_as_float(((unsigned)b) << 16);
}

// ---------------- CSR build (arena partition; no pre-histogram) ----------------

// Coarse partition into dst>>8 buckets, each bucket appending into its private
// arena [b*CAP, ...). Per-wave LDS counters; int4-vectorized edge loads.
// Record packed to 4B: src<<8 | (dst & 255)   (src < 2^17 -> 25 bits).
__global__ __launch_bounds__(256) void partition_kernel(
        const int* __restrict__ src, const int* __restrict__ dst, int e,
        int* __restrict__ gcur, int* __restrict__ part, int nbkt) {
    __shared__ int cnt[4][392];
    __shared__ int base_l[4][392];
    int t = threadIdx.x;
    int wv = t >> 6;
    int cb = blockIdx.x * (256 * P1_EPT);
    for (int i = t; i < 4 * 392; i += 256) ((int*)cnt)[i] = 0;
    __syncthreads();
    int sr[P1_EPT], ds[P1_EPT], rk[P1_EPT];
#pragma unroll
    for (int i4 = 0; i4 < P1_EPT / 4; ++i4) {
        int eid0 = cb + (i4 * 256 + t) * 4;
        int4 s4, d4;
        bool full = (eid0 + 3 < e);
        if (full) {
            s4 = *(const int4*)(src + eid0);
            d4 = *(const int4*)(dst + eid0);
        }
#pragma unroll
        for (int j = 0; j < 4; ++j) {
            int i = i4 * 4 + j;
            int eid = eid0 + j;
            if (full) {
                sr[i] = (&s4.x)[j];
                ds[i] = (&d4.x)[j];
            } else if (eid < e) {
                sr[i] = src[eid];
                ds[i] = dst[eid];
            }
            rk[i] = (eid < e) ? atomicAdd(&cnt[wv][ds[i] >> BKT_SHIFT], 1) : -1;
        }
    }
    __syncthreads();
    for (int b = t; b < nbkt; b += 256) {
        int c0 = cnt[0][b], c1 = cnt[1][b], c2 = cnt[2][b], c3 = cnt[3][b];
        int tot = c0 + c1 + c2 + c3;
        if (tot > 0) {
            int gb = atomicAdd(&gcur[b], tot);
            base_l[0][b] = gb;
            base_l[1][b] = gb + c0;
            base_l[2][b] = gb + c0 + c1;
            base_l[3][b] = gb + c0 + c1 + c2;
        }
    }
    __syncthreads();
#pragma unroll
    for (int i = 0; i < P1_EPT; ++i) {
        if (rk[i] >= 0) {
            int b = ds[i] >> BKT_SHIFT;
            part[base_l[wv][b] + rk[i]] = (sr[i] << BKT_SHIFT) | (ds[i] & (BKT_SIZE - 1));
        }
    }
}

// 1 block x 256: bucket counts from cursors, exclusive scan -> bbase[0..nbkt].
__global__ void cnt_scan(const int* __restrict__ gcur, int* __restrict__ bbase,
                         int nbkt, int e_total) {
    __shared__ int tmp[256];
    int t = threadIdx.x;
    int b0 = 2 * t, b1 = 2 * t + 1;
    int c0 = (b0 < nbkt) ? (gcur[b0] - b0 * BKT_CAP) : 0;
    int c1 = (b1 < nbkt) ? (gcur[b1] - b1 * BKT_CAP) : 0;
    int s = c0 + c1;
    tmp[t] = s;
    __syncthreads();
    for (int o = 1; o < 256; o <<= 1) {
        int x = tmp[t];
        int y = (t >= o) ? tmp[t - o] : 0;
        __syncthreads();
        tmp[t] = x + y;
        __syncthreads();
    }
    int excl = tmp[t] - s;
    if (b0 < nbkt) bbase[b0] = excl;
    if (b1 < nbkt) bbase[b1] = excl + c0;
    if (t == 0) bbase[nbkt] = e_total;
}

// Per bucket (256 dst nodes): per-dst counts in LDS, 256-scan, write row_off
// slice (coalesced) + scatter into the bucket's L2-resident csr window.
__global__ __launch_bounds__(256) void finesort2(
        const int* __restrict__ part, const int* __restrict__ gcur,
        const int* __restrict__ bbase, int* __restrict__ row_off,
        int* __restrict__ csr_src, int n, int e_total, int nbkt) {
    __shared__ int cnt[BKT_SIZE];
    __shared__ int cur[BKT_SIZE];
    __shared__ int tmp[BKT_SIZE];
    int b = blockIdx.x, t = threadIdx.x;
    int d0 = b << BKT_SHIFT;
    int nloc = min(BKT_SIZE, n - d0);
    cnt[t] = 0;
    __syncthreads();
    int abase = b * BKT_CAP, aend = gcur[b];
    for (int i = abase + t; i < aend; i += 256)
        atomicAdd(&cnt[part[i] & (BKT_SIZE - 1)], 1);
    __syncthreads();
    int c = cnt[t];
    tmp[t] = c;
    __syncthreads();
    for (int o = 1; o < 256; o <<= 1) {
        int x = tmp[t];
        int y = (t >= o) ? tmp[t - o] : 0;
        __syncthreads();
        tmp[t] = x + y;
        __syncthreads();
    }
    int pos0 = bbase[b] + tmp[t] - c;
    cur[t] = pos0;
    if (t < nloc) row_off[d0 + t] = pos0;
    if (b == nbkt - 1 && t == 0) row_off[n] = e_total;
    __syncthreads();
    for (int i = abase + t; i < aend; i += 256) {
        int pk = part[i];
        int pos = atomicAdd(&cur[pk & (BKT_SIZE - 1)], 1);
        csr_src[pos] = ((unsigned)pk) >> BKT_SHIFT;
    }
}

// ---------------- combined prep: W decomposition + gcur init (1 launch) ----------------
__device__ inline void wprep_body(const float* __restrict__ W, unsigned short* __restrict__ wh,
                                  unsigned short* __restrict__ wl, int K, int idx) {
    int KT = K / 32;
    if (idx >= KT * 4 * 64) return;
    int lane = idx & 63;
    int fbkt = idx >> 6;
    int fb = fbkt & 3, kt = fbkt >> 2;
    int q = lane >> 4, c = lane & 15;
    for (int j = 0; j < 8; ++j) {
        float w = W[(kt * 32 + q * 8 + j) * 64 + fb * 16 + c];
        unsigned short hi = f2bf(w);
        wh[idx * 8 + j] = hi;
        wl[idx * 8 + j] = f2bf(w - bf2f(hi));
    }
}

__global__ void prep_kernel(const float* __restrict__ W1, unsigned short* __restrict__ w1h,
                            unsigned short* __restrict__ w1l,
                            const float* __restrict__ W2, unsigned short* __restrict__ w2h,
                            unsigned short* __restrict__ w2l,
                            int* __restrict__ gcur, int nbkt) {
    int b = blockIdx.x, t = threadIdx.x;
    if (b < 4) {
        wprep_body(W1, w1h, w1l, 128, b * 256 + t);
    } else if (b < 6) {
        wprep_body(W2, w2h, w2l, 64, (b - 4) * 256 + t);
    } else {
        int i = (b - 6) * 256 + t;
        if (i < nbkt) gcur[i] = i * BKT_CAP;
    }
}

// ---------------- MFMA GEMM + attention dots ----------------
// h[N,64] = x[N,K] @ W[K,64] via v_mfma_f32_16x16x32_bf16, bf16x3 split.
// IN = float (layer1) or __half (layer2; fp16 splits into bf16 hi+lo exactly).
template <int KT, typename IN>
__global__ __launch_bounds__(256) void gemm_mfma_kernel(
        const IN* __restrict__ x, const unsigned short* __restrict__ wh,
        const unsigned short* __restrict__ wl,
        const float* __restrict__ al, const float* __restrict__ ar,
        __half* __restrict__ h16, float* __restrict__ el,
        float* __restrict__ er, int n) {
    constexpr int K = KT * 32;
    constexpr int WFRAG = KT * 4 * 64 * 8;   // shorts
    __shared__ unsigned short Wh[WFRAG];
    __shared__ unsigned short Wl[WFRAG];
    for (int i = threadIdx.x; i < WFRAG / 8; i += 256) {
        ((float4*)Wh)[i] = ((const float4*)wh)[i];
        ((float4*)Wl)[i] = ((const float4*)wl)[i];
    }
    __syncthreads();

    int lane = threadIdx.x & 63;
    int q = lane >> 4, c = lane & 15;
    int wave = (int)((blockIdx.x * blockDim.x + threadIdx.x) >> 6);
    int nwaves = (gridDim.x * blockDim.x) >> 6;
    int ntiles = (n + 15) >> 4;

    float alv[4], arv[4];
#pragma unroll
    for (int fb = 0; fb < 4; ++fb) {
        alv[fb] = al[fb * 16 + c];
        arv[fb] = ar[fb * 16 + c];
    }

    for (int t = wave; t < ntiles; t += nwaves) {
        int v0 = t * 16;
        int row = min(v0 + c, n - 1);
        const IN* xr = x + (size_t)row * K + q * 8;

        short8 Ah[KT], Al[KT];
#pragma unroll
        for (int kt = 0; kt < KT; ++kt) {
            float xv[8];
            if constexpr (std::is_same<IN, float>::value) {
                *(float4*)&xv[0] = *(const float4*)(xr + kt * 32);
                *(float4*)&xv[4] = *(const float4*)(xr + kt * 32 + 4);
            } else {
                __half hh[8];
                *(uint4*)hh = *(const uint4*)(xr + kt * 32);
#pragma unroll
                for (int j = 0; j < 8; ++j) xv[j] = __half2float(hh[j]);
            }
#pragma unroll
            for (int j = 0; j < 8; ++j) {
                unsigned short hi = f2bf(xv[j]);
                Ah[kt][j] = (short)hi;
                Al[kt][j] = (short)f2bf(xv[j] - bf2f(hi));
            }
        }

        float4v acc[4];
#pragma unroll
        for (int fb = 0; fb < 4; ++fb) acc[fb] = (float4v)0.f;

#pragma unroll
        for (int kt = 0; kt < KT; ++kt) {
#pragma unroll
            for (int fb = 0; fb < 4; ++fb) {
                short8 bh = *(const short8*)&Wh[((kt * 4 + fb) * 64 + lane) * 8];
                short8 bl = *(const short8*)&Wl[((kt * 4 + fb) * 64 + lane) * 8];
                acc[fb] = __builtin_amdgcn_mfma_f32_16x16x32_bf16(Ah[kt], bh, acc[fb], 0, 0, 0);
                acc[fb] = __builtin_amdgcn_mfma_f32_16x16x32_bf16(Al[kt], bh, acc[fb], 0, 0, 0);
                acc[fb] = __builtin_amdgcn_mfma_f32_16x16x32_bf16(Ah[kt], bl, acc[fb], 0, 0, 0);
            }
        }

#pragma unroll
        for (int r = 0; r < 4; ++r) {
            int v = v0 + q * 4 + r;
            float pl = 0.f, pr = 0.f;
            bool ok = (v < n);
#pragma unroll
            for (int fb = 0; fb < 4; ++fb) {
                float hv = acc[fb][r];
                if (ok) h16[(size_t)v * 64 + fb * 16 + c] = __float2half(hv);
                pl = fmaf(hv, alv[fb], pl);
                pr = fmaf(hv, arv[fb], pr);
            }
#pragma unroll
            for (int off = 8; off > 0; off >>= 1) {
                pl += __shfl_xor(pl, off);
                pr += __shfl_xor(pr, off);
            }
            if (ok && c == 0) { el[v] = pl; er[v] = pr; }
        }
    }
}

// ---------------- softmax-aggregate ----------------
// Two independent dst nodes interleaved per wave (doubles memory-level
// parallelism: ~8 h-row gathers in flight instead of 4, and node A's compute
// hides node B's dependent-load chain). 4 edges per 16-lane group step,
// uint2 = 4 fp16 features per lane.
// OUT = __half (layer1: relu'd hr) or float (layer2: d_out).
template <typename OUT>
__global__ __launch_bounds__(256) void agg_kernel(
        const int* __restrict__ row_off, const int* __restrict__ csr_src,
        const __half* __restrict__ h16, const float* __restrict__ el,
        const float* __restrict__ er, const float* __restrict__ bias,
        OUT* __restrict__ out, int n, int do_relu) {
    int lane = threadIdx.x & 63;
    int grp = lane >> 4;      // 0..3: edge slot within a 4-edge step
    int c = lane & 15;        // feature quad: features 4c..4c+3
    int gwave = rfl_i((int)((blockIdx.x * blockDim.x + threadIdx.x) >> 6));
    int nwaves = (gridDim.x * blockDim.x) >> 6;
    const uint2* __restrict__ h2 = (const uint2*)h16;
    float4 b4 = ((const float4*)bias)[c];

    for (int vb = gwave; vb < n; vb += 2 * nwaves) {
        bool act1 = (vb + nwaves) < n;
        int va[2];
        va[0] = vb;
        va[1] = act1 ? (vb + nwaves) : vb;

        int rs[2], re[2];
        float erv[2];
#pragma unroll
        for (int k = 0; k < 2; ++k) {
            rs[k] = rfl_i(row_off[va[k]]);
            re[k] = rfl_i(row_off[va[k] + 1]);
            erv[k] = er[va[k]];
        }
        if (!act1) re[1] = rs[1];   // node 1 inactive -> zero edges

        float a0[2] = {0.f, 0.f}, a1[2] = {0.f, 0.f};
        float a2[2] = {0.f, 0.f}, a3[2] = {0.f, 0.f};
        float ssum[2] = {0.f, 0.f};
        int base[2] = {rs[0], rs[1]};

        while (base[0] < re[0] || base[1] < re[1]) {
            int cnt[2], cnt16[2], s_e[2];
            float ex[2];
            // issue both csr_src loads first
#pragma unroll
            for (int k = 0; k < 2; ++k) {
                cnt[k] = min(64, re[k] - base[k]);
                if (cnt[k] < 0) cnt[k] = 0;
                cnt16[k] = (cnt[k] + 15) & ~15;
                s_e[k] = 0;
                ex[k] = 0.f;
                if (lane < cnt[k]) s_e[k] = csr_src[base[k] + lane];
            }
            // both el gathers in flight before either expf
#pragma unroll
            for (int k = 0; k < 2; ++k) {
                if (lane < cnt[k]) {
                    float ev = el[s_e[k]] + erv[k];
                    ev = (ev >= 0.f) ? ev : NEG_SLOPE * ev;
                    ex[k] = __expf(ev);
                }
            }
#pragma unroll
            for (int k = 0; k < 2; ++k) {
                float cs = ex[k];
#pragma unroll
                for (int off = 32; off > 0; off >>= 1) cs += __shfl_xor(cs, off);
                ssum[k] += cs;
            }
            int jmax = max(cnt16[0], cnt16[1]);
            for (int j = 0; j < jmax; j += 16) {
                int sj[2][4];
                float exj[2][4];
                uint2 hv[2][4];
                // issue all (up to 8) h-row gathers before consuming any
#pragma unroll
                for (int k = 0; k < 2; ++k) {
                    if (j < cnt16[k]) {
#pragma unroll
                        for (int u = 0; u < 4; ++u) {
                            int idx = j + 4 * u + grp;
                            sj[k][u] = __shfl(s_e[k], idx);
                            exj[k][u] = __shfl(ex[k], idx);
                            hv[k][u] = h2[sj[k][u] * 16 + c];
                        }
                    }
                }
#pragma unroll
                for (int k = 0; k < 2; ++k) {
                    if (j < cnt16[k]) {
#pragma unroll
                        for (int u = 0; u < 4; ++u) {
                            float2 f01 = __half22float2(*(__half2*)&hv[k][u].x);
                            float2 f23 = __half22float2(*(__half2*)&hv[k][u].y);
                            a0[k] = fmaf(exj[k][u], f01.x, a0[k]);
                            a1[k] = fmaf(exj[k][u], f01.y, a1[k]);
                            a2[k] = fmaf(exj[k][u], f23.x, a2[k]);
                            a3[k] = fmaf(exj[k][u], f23.y, a3[k]);
                        }
                    }
                }
            }
            base[0] += 64;
            base[1] += 64;
        }

        // combine the 4 edge-groups per node: reduce over lane bits 4,5
#pragma unroll
        for (int k = 0; k < 2; ++k) {
            if (k == 1 && !act1) break;
#pragma unroll
            for (int off = 16; off < 64; off <<= 1) {
                a0[k] += __shfl_xor(a0[k], off);
                a1[k] += __shfl_xor(a1[k], off);
                a2[k] += __shfl_xor(a2[k], off);
                a3[k] += __shfl_xor(a3[k], off);
            }
            if (lane < 16) {
                float4 o;
                if (re[k] > rs[k]) {
                    float inv = 1.0f / ssum[k];
                    o.x = fmaf(a0[k], inv, b4.x);
                    o.y = fmaf(a1[k], inv, b4.y);
                    o.z = fmaf(a2[k], inv, b4.z);
                    o.w = fmaf(a3[k], inv, b4.w);
                } else {
                    o = b4;
                }
                if (do_relu) {
                    o.x = fmaxf(o.x, 0.f);
                    o.y = fmaxf(o.y, 0.f);
                    o.z = fmaxf(o.z, 0.f);
                    o.w = fmaxf(o.w, 0.f);
                }
                if constexpr (std::is_same<OUT, __half>::value) {
                    uint2 pk;
                    *(__half2*)&pk.x = __float22half2_rn(make_float2(o.x, o.y));
                    *(__half2*)&pk.y = __float22half2_rn(make_float2(o.z, o.w));
                    ((uint2*)(out + (size_t)va[k] * 64))[c] = pk;
                } else {
                    ((float4*)(out + (size_t)va[k] * 64))[c] = o;
                }
            }
        }
    }
}

extern "C" void kernel_launch(void* const* d_in, const int* in_sizes, int n_in,
                              void* d_out, int out_size, void* d_ws, size_t ws_size,
                              hipStream_t stream) {
    (void)n_in; (void)out_size; (void)ws_size;
    const float* features = (const float*)d_in[0];
    // d_in[1] = edge_weights, unused by the reference forward
    const int*   src = (const int*)d_in[2];
    const int*   dst = (const int*)d_in[3];
    const float* W1  = (const float*)d_in[4];
    const float* al1 = (const float*)d_in[5];
    const float* ar1 = (const float*)d_in[6];
    const float* b1  = (const float*)d_in[7];
    const float* W2  = (const float*)d_in[8];
    const float* al2 = (const float*)d_in[9];
    const float* ar2 = (const float*)d_in[10];
    const float* b2  = (const float*)d_in[11];

    const int n = in_sizes[0] / 128;   // 100000
    const int e = in_sizes[2];         // 1600000
    float* out = (float*)d_out;

    char* p = (char*)d_ws;
    auto alloc = [&](size_t bytes) -> char* {
        char* q = p;
        p += (bytes + 255) & ~(size_t)255;
        return q;
    };
    int*    row_off = (int*)alloc((size_t)(n + 1) * 4);
    int*    csr_src = (int*)alloc((size_t)e * 4);
    __half* h16     = (__half*)alloc((size_t)n * 64 * 2);
    __half* hr      = (__half*)alloc((size_t)n * 64 * 2);
    float*  el      = (float*)alloc((size_t)n * 4);
    float*  er      = (float*)alloc((size_t)n * 4);
    int*    gcur    = (int*)alloc(512 * 4);
    int*    bbase   = (int*)alloc(513 * 4);
    unsigned short* w1h = (unsigned short*)alloc(4 * 4 * 64 * 8 * 2);
    unsigned short* w1l = (unsigned short*)alloc(4 * 4 * 64 * 8 * 2);
    unsigned short* w2h = (unsigned short*)alloc(2 * 4 * 64 * 8 * 2);
    unsigned short* w2l = (unsigned short*)alloc(2 * 4 * 64 * 8 * 2);
    // arena (nbkt*CAP ints = 19.2MB) aliases h16+hr (25.6MB contiguous):
    // consumed by finesort2 before gemm1/agg1 write h16/hr.
    int*    part    = (int*)h16;

    const int nbkt = (n + BKT_SIZE - 1) >> BKT_SHIFT;   // 391

    // W decomposition + gcur init (one launch: blocks 0-3=W1, 4-5=W2, 6-7=gcur)
    prep_kernel<<<8, 256, 0, stream>>>(W1, w1h, w1l, W2, w2h, w2l, gcur, nbkt);

    // CSR by dst (shared by both layers)
    partition_kernel<<<(e + 256 * P1_EPT - 1) / (256 * P1_EPT), 256, 0, stream>>>(
        src, dst, e, gcur, part, nbkt);
    cnt_scan<<<1, 256, 0, stream>>>(gcur, bbase, nbkt, e);
    finesort2<<<nbkt, 256, 0, stream>>>(part, gcur, bbase, row_off, csr_src, n, e, nbkt);

    // layer 1
    gemm_mfma_kernel<4, float><<<512, 256, 0, stream>>>(features, w1h, w1l, al1, ar1,
                                                        h16, el, er, n);
    agg_kernel<__half><<<2048, 256, 0, stream>>>(row_off, csr_src, h16, el, er, b1, hr, n, 1);

    // layer 2
    gemm_mfma_kernel<2, __half><<<512, 256, 0, stream>>>(hr, w2h, w2l, al2, ar2,
                                                         h16, el, er, n);
    agg_kernel<float><<<2048, 256, 0, stream>>>(row_off, csr_src, h16, el, er, b2, out, n, 0);
}

// Round 2
// 244.277 us; speedup vs baseline: 1.0708x; 1.0708x over previous
//
#include <hip/hip_runtime.h>
#include <hip/hip_fp16.h>
#include <type_traits>

#define NEG_SLOPE 0.2f
#define BKT_SHIFT 8
#define BKT_SIZE (1 << BKT_SHIFT)     // 256 dst nodes per bucket
#define BKT_CAP 12288                 // arena slots/bucket (mean 4096; overflow ~impossible)
#define P1_EPT 16                     // edges per thread in partition pass

typedef __attribute__((ext_vector_type(8))) short short8;
typedef __attribute__((ext_vector_type(4))) float float4v;

__device__ inline int rfl_i(int v) { return __builtin_amdgcn_readfirstlane(v); }

// round-to-nearest-even fp32 -> bf16
__device__ inline unsigned short f2bf(float f) {
    unsigned u = __float_as_uint(f);
    unsigned r = u + 0x7FFFu + ((u >> 16) & 1u);
    return (unsigned short)(r >> 16);
}
__device__ inline float bf2f(unsigned short b) {
    return __uint_as_float(((unsigned)b) << 16);
}

// ---------------- partition body (arena by dst>>8; gcur = pure counts) ----------------
// Record packed to 4B: src<<8 | (dst & 255)   (src < 2^17 -> 25 bits).
__device__ __forceinline__ void partition_body(
        const int* __restrict__ src, const int* __restrict__ dst, int e,
        int* __restrict__ gcur, int* __restrict__ part, int nbkt, int b_id,
        char* smem) {
    int (*cnt)[392]    = (int(*)[392])smem;
    int (*base_l)[392] = (int(*)[392])(smem + 4 * 392 * sizeof(int));
    int t = threadIdx.x;
    int wv = t >> 6;
    int cb = b_id * (256 * P1_EPT);
    for (int i = t; i < 4 * 392; i += 256) ((int*)cnt)[i] = 0;
    __syncthreads();
    int sr[P1_EPT], ds[P1_EPT], rk[P1_EPT];
#pragma unroll
    for (int i4 = 0; i4 < P1_EPT / 4; ++i4) {
        int eid0 = cb + (i4 * 256 + t) * 4;
        int4 s4, d4;
        bool full = (eid0 + 3 < e);
        if (full) {
            s4 = *(const int4*)(src + eid0);
            d4 = *(const int4*)(dst + eid0);
        }
#pragma unroll
        for (int j = 0; j < 4; ++j) {
            int i = i4 * 4 + j;
            int eid = eid0 + j;
            if (full) {
                sr[i] = (&s4.x)[j];
                ds[i] = (&d4.x)[j];
            } else if (eid < e) {
                sr[i] = src[eid];
                ds[i] = dst[eid];
            }
            rk[i] = (eid < e) ? atomicAdd(&cnt[wv][ds[i] >> BKT_SHIFT], 1) : -1;
        }
    }
    __syncthreads();
    for (int b = t; b < nbkt; b += 256) {
        int c0 = cnt[0][b], c1 = cnt[1][b], c2 = cnt[2][b], c3 = cnt[3][b];
        int tot = c0 + c1 + c2 + c3;
        if (tot > 0) {
            int gb = b * BKT_CAP + atomicAdd(&gcur[b], tot);
            base_l[0][b] = gb;
            base_l[1][b] = gb + c0;
            base_l[2][b] = gb + c0 + c1;
            base_l[3][b] = gb + c0 + c1 + c2;
        }
    }
    __syncthreads();
#pragma unroll
    for (int i = 0; i < P1_EPT; ++i) {
        if (rk[i] >= 0) {
            int b = ds[i] >> BKT_SHIFT;
            part[base_l[wv][b] + rk[i]] = (sr[i] << BKT_SHIFT) | (ds[i] & (BKT_SIZE - 1));
        }
    }
}

// ---------------- finesort (fused bbase scan; no separate cnt_scan) ----------------
__global__ __launch_bounds__(256) void finesort3(
        const int* __restrict__ part, const int* __restrict__ gcur,
        int* __restrict__ row_off, int* __restrict__ csr_src,
        int n, int e_total, int nbkt) {
    __shared__ int cnt[BKT_SIZE];
    __shared__ int cur[BKT_SIZE];
    __shared__ int tmp[BKT_SIZE];
    int b = blockIdx.x, t = threadIdx.x;
    // bbase = sum of gcur[0..b)  (gcur holds pure counts)
    int i1 = 256 + t;
    int v0 = (t < b) ? gcur[t] : 0;
    int v1 = (i1 < b) ? gcur[i1] : 0;
    tmp[t] = v0 + v1;
    __syncthreads();
    for (int o = 128; o > 0; o >>= 1) {
        if (t < o) tmp[t] += tmp[t + o];
        __syncthreads();
    }
    int bbase_b = tmp[0];
    __syncthreads();

    int d0 = b << BKT_SHIFT;
    int nloc = min(BKT_SIZE, n - d0);
    cnt[t] = 0;
    __syncthreads();
    int abase = b * BKT_CAP, aend = abase + gcur[b];
    for (int i = abase + t; i < aend; i += 256)
        atomicAdd(&cnt[part[i] & (BKT_SIZE - 1)], 1);
    __syncthreads();
    int c = cnt[t];
    tmp[t] = c;
    __syncthreads();
    for (int o = 1; o < 256; o <<= 1) {
        int x = tmp[t];
        int y = (t >= o) ? tmp[t - o] : 0;
        __syncthreads();
        tmp[t] = x + y;
        __syncthreads();
    }
    int pos0 = bbase_b + tmp[t] - c;
    cur[t] = pos0;
    if (t < nloc) row_off[d0 + t] = pos0;
    if (b == nbkt - 1 && t == 0) row_off[n] = e_total;
    __syncthreads();
    for (int i = abase + t; i < aend; i += 256) {
        int pk = part[i];
        int pos = atomicAdd(&cur[pk & (BKT_SIZE - 1)], 1);
        csr_src[pos] = ((unsigned)pk) >> BKT_SHIFT;
    }
}

// ---------------- MFMA GEMM body (in-kernel W decomposition) ----------------
// h[N,64] = x[N,K] @ W[K,64] via v_mfma_f32_16x16x32_bf16, bf16x3 split.
// IN = float (layer1) or __half (layer2; fp16 splits into bf16 hi+lo exactly).
template <int KT, typename IN>
__device__ __forceinline__ void gemm_body(
        const IN* __restrict__ x, const float* __restrict__ W,
        const float* __restrict__ al, const float* __restrict__ ar,
        __half* __restrict__ h16, float* __restrict__ el,
        float* __restrict__ er, int n, int bid, int nblocks, char* smem) {
    constexpr int K = KT * 32;
    constexpr int WFRAG = KT * 4 * 64 * 8;   // shorts
    unsigned short* Wh = (unsigned short*)smem;
    unsigned short* Wl = Wh + WFRAG;
    // decompose W (raw fp32, [K,64]) into MFMA frag order, bf16 hi/lo, in LDS
    for (int idx = threadIdx.x; idx < KT * 4 * 64; idx += 256) {
        int lane = idx & 63, fbkt = idx >> 6;
        int fb = fbkt & 3, kt = fbkt >> 2;
        int q = lane >> 4, c = lane & 15;
#pragma unroll
        for (int j = 0; j < 8; ++j) {
            float w = W[(kt * 32 + q * 8 + j) * 64 + fb * 16 + c];
            unsigned short hi = f2bf(w);
            Wh[idx * 8 + j] = hi;
            Wl[idx * 8 + j] = f2bf(w - bf2f(hi));
        }
    }
    __syncthreads();

    int lane = threadIdx.x & 63;
    int q = lane >> 4, c = lane & 15;
    int wave = bid * 4 + (int)(threadIdx.x >> 6);
    int nwaves = nblocks * 4;
    int ntiles = (n + 15) >> 4;

    float alv[4], arv[4];
#pragma unroll
    for (int fb = 0; fb < 4; ++fb) {
        alv[fb] = al[fb * 16 + c];
        arv[fb] = ar[fb * 16 + c];
    }

    for (int t = wave; t < ntiles; t += nwaves) {
        int v0 = t * 16;
        int row = min(v0 + c, n - 1);
        const IN* xr = x + (size_t)row * K + q * 8;

        short8 Ah[KT], Al[KT];
#pragma unroll
        for (int kt = 0; kt < KT; ++kt) {
            float xv[8];
            if constexpr (std::is_same<IN, float>::value) {
                *(float4*)&xv[0] = *(const float4*)(xr + kt * 32);
                *(float4*)&xv[4] = *(const float4*)(xr + kt * 32 + 4);
            } else {
                __half hh[8];
                *(uint4*)hh = *(const uint4*)(xr + kt * 32);
#pragma unroll
                for (int j = 0; j < 8; ++j) xv[j] = __half2float(hh[j]);
            }
#pragma unroll
            for (int j = 0; j < 8; ++j) {
                unsigned short hi = f2bf(xv[j]);
                Ah[kt][j] = (short)hi;
                Al[kt][j] = (short)f2bf(xv[j] - bf2f(hi));
            }
        }

        float4v acc[4];
#pragma unroll
        for (int fb = 0; fb < 4; ++fb) acc[fb] = (float4v)0.f;

#pragma unroll
        for (int kt = 0; kt < KT; ++kt) {
#pragma unroll
            for (int fb = 0; fb < 4; ++fb) {
                short8 bh = *(const short8*)&Wh[((kt * 4 + fb) * 64 + lane) * 8];
                short8 bl = *(const short8*)&Wl[((kt * 4 + fb) * 64 + lane) * 8];
                acc[fb] = __builtin_amdgcn_mfma_f32_16x16x32_bf16(Ah[kt], bh, acc[fb], 0, 0, 0);
                acc[fb] = __builtin_amdgcn_mfma_f32_16x16x32_bf16(Al[kt], bh, acc[fb], 0, 0, 0);
                acc[fb] = __builtin_amdgcn_mfma_f32_16x16x32_bf16(Ah[kt], bl, acc[fb], 0, 0, 0);
            }
        }

#pragma unroll
        for (int r = 0; r < 4; ++r) {
            int v = v0 + q * 4 + r;
            float pl = 0.f, pr = 0.f;
            bool ok = (v < n);
#pragma unroll
            for (int fb = 0; fb < 4; ++fb) {
                float hv = acc[fb][r];
                if (ok) h16[(size_t)v * 64 + fb * 16 + c] = __float2half(hv);
                pl = fmaf(hv, alv[fb], pl);
                pr = fmaf(hv, arv[fb], pr);
            }
#pragma unroll
            for (int off = 8; off > 0; off >>= 1) {
                pl += __shfl_xor(pl, off);
                pr += __shfl_xor(pr, off);
            }
            if (ok && c == 0) { el[v] = pl; er[v] = pr; }
        }
    }
}

// fused: blocks [0,npb) = partition, [npb, grid) = gemm layer1.
// Disjoint memory: partition writes arena(d_out)+gcur; gemm writes h16/el/er.
__global__ __launch_bounds__(256) void part_gemm1(
        const int* __restrict__ src, const int* __restrict__ dst, int e,
        int* __restrict__ gcur, int* __restrict__ part, int nbkt, int npb,
        const float* __restrict__ x, const float* __restrict__ W1,
        const float* __restrict__ al, const float* __restrict__ ar,
        __half* __restrict__ h16, float* __restrict__ el,
        float* __restrict__ er, int n) {
    __shared__ char smem[32768];   // max(partition 12.5KB, gemm KT=4 32KB)
    int b = (int)blockIdx.x;
    if (b < npb)
        partition_body(src, dst, e, gcur, part, nbkt, b, smem);
    else
        gemm_body<4, float>(x, W1, al, ar, h16, el, er, n, b - npb,
                            (int)gridDim.x - npb, smem);
}

template <int KT, typename IN>
__global__ __launch_bounds__(256) void gemm_mfma_kernel(
        const IN* __restrict__ x, const float* __restrict__ W,
        const float* __restrict__ al, const float* __restrict__ ar,
        __half* __restrict__ h16, float* __restrict__ el,
        float* __restrict__ er, int n) {
    __shared__ char smem[KT * 4 * 64 * 8 * 2 * 2];
    gemm_body<KT, IN>(x, W, al, ar, h16, el, er, n, (int)blockIdx.x,
                      (int)gridDim.x, smem);
}

// ---------------- softmax-aggregate (round-0 form: 1 node/wave, 4096 blocks) ----------------
// 4 edges per wave step (16-lane groups, uint2 = 4 fp16 features per lane).
// OUT = __half (layer1: relu'd hr) or float (layer2: d_out).
template <typename OUT>
__global__ __launch_bounds__(256) void agg_kernel(
        const int* __restrict__ row_off, const int* __restrict__ csr_src,
        const __half* __restrict__ h16, const float* __restrict__ el,
        const float* __restrict__ er, const float* __restrict__ bias,
        OUT* __restrict__ out, int n, int do_relu) {
    int lane = threadIdx.x & 63;
    int grp = lane >> 4;      // 0..3: edge slot within a 4-edge step
    int c = lane & 15;        // feature quad: features 4c..4c+3
    int gwave = rfl_i((int)((blockIdx.x * blockDim.x + threadIdx.x) >> 6));
    int nwaves = (gridDim.x * blockDim.x) >> 6;
    float4 b4 = ((const float4*)bias)[c];
    for (int v = gwave; v < n; v += nwaves) {
        int rs = rfl_i(row_off[v]), re = rfl_i(row_off[v + 1]);
        float er_v = er[v];
        float a0 = 0.f, a1 = 0.f, a2 = 0.f, a3 = 0.f, ssum = 0.f;
        for (int base = rs; base < re; base += 64) {
            int cnt = min(64, re - base);
            int s_e = 0;
            float ex = 0.f;
            if (lane < cnt) {
                s_e = csr_src[base + lane];
                float ev = el[s_e] + er_v;
                ev = (ev >= 0.f) ? ev : NEG_SLOPE * ev;
                ex = __expf(ev);
            }
            float cs = ex;
#pragma unroll
            for (int off = 32; off > 0; off >>= 1) cs += __shfl_xor(cs, off);
            ssum += cs;
            int cnt16 = (cnt + 15) & ~15;
            for (int j = 0; j < cnt16; j += 16) {
                int sj[4];
                float exj[4];
                uint2 hv[4];
#pragma unroll
                for (int u = 0; u < 4; ++u) {
                    int idx = j + 4 * u + grp;
                    sj[u] = __shfl(s_e, idx);
                    exj[u] = __shfl(ex, idx);
                    hv[u] = *((const uint2*)(h16 + (size_t)sj[u] * 64) + c);
                }
#pragma unroll
                for (int u = 0; u < 4; ++u) {
                    float2 f01 = __half22float2(*(__half2*)&hv[u].x);
                    float2 f23 = __half22float2(*(__half2*)&hv[u].y);
                    a0 = fmaf(exj[u], f01.x, a0);
                    a1 = fmaf(exj[u], f01.y, a1);
                    a2 = fmaf(exj[u], f23.x, a2);
                    a3 = fmaf(exj[u], f23.y, a3);
                }
            }
        }
        // combine the 4 edge-groups: reduce over lane bits 4,5
#pragma unroll
        for (int off = 16; off < 64; off <<= 1) {
            a0 += __shfl_xor(a0, off);
            a1 += __shfl_xor(a1, off);
            a2 += __shfl_xor(a2, off);
            a3 += __shfl_xor(a3, off);
        }
        if (lane < 16) {
            float4 o;
            if (re > rs) {
                float inv = 1.0f / ssum;
                o.x = fmaf(a0, inv, b4.x);
                o.y = fmaf(a1, inv, b4.y);
                o.z = fmaf(a2, inv, b4.z);
                o.w = fmaf(a3, inv, b4.w);
            } else {
                o = b4;
            }
            if (do_relu) {
                o.x = fmaxf(o.x, 0.f);
                o.y = fmaxf(o.y, 0.f);
                o.z = fmaxf(o.z, 0.f);
                o.w = fmaxf(o.w, 0.f);
            }
            if constexpr (std::is_same<OUT, __half>::value) {
                uint2 pk;
                *(__half2*)&pk.x = __float22half2_rn(make_float2(o.x, o.y));
                *(__half2*)&pk.y = __float22half2_rn(make_float2(o.z, o.w));
                ((uint2*)(out + (size_t)v * 64))[c] = pk;
            } else {
                ((float4*)(out + (size_t)v * 64))[c] = o;
            }
        }
    }
}

extern "C" void kernel_launch(void* const* d_in, const int* in_sizes, int n_in,
                              void* d_out, int out_size, void* d_ws, size_t ws_size,
                              hipStream_t stream) {
    (void)n_in; (void)out_size; (void)ws_size;
    const float* features = (const float*)d_in[0];
    // d_in[1] = edge_weights, unused by the reference forward
    const int*   src = (const int*)d_in[2];
    const int*   dst = (const int*)d_in[3];
    const float* W1  = (const float*)d_in[4];
    const float* al1 = (const float*)d_in[5];
    const float* ar1 = (const float*)d_in[6];
    const float* b1  = (const float*)d_in[7];
    const float* W2  = (const float*)d_in[8];
    const float* al2 = (const float*)d_in[9];
    const float* ar2 = (const float*)d_in[10];
    const float* b2  = (const float*)d_in[11];

    const int n = in_sizes[0] / 128;   // 100000
    const int e = in_sizes[2];         // 1600000
    float* out = (float*)d_out;

    char* p = (char*)d_ws;
    auto alloc = [&](size_t bytes) -> char* {
        char* q = p;
        p += (bytes + 255) & ~(size_t)255;
        return q;
    };
    int*    row_off = (int*)alloc((size_t)(n + 1) * 4);
    int*    csr_src = (int*)alloc((size_t)e * 4);
    __half* h16     = (__half*)alloc((size_t)n * 64 * 2);
    __half* hr      = (__half*)alloc((size_t)n * 64 * 2);
    float*  el      = (float*)alloc((size_t)n * 4);
    float*  er      = (float*)alloc((size_t)n * 4);
    int*    gcur    = (int*)alloc(512 * 4);
    // arena (nbkt*CAP ints = 19.2MB) lives in d_out (25.6MB): only written by
    // agg2 at the very end; partition/finesort consume it long before.
    // (h16 can no longer host it: gemm1 runs concurrently with partition.)
    int*    part    = (int*)d_out;

    const int nbkt = (n + BKT_SIZE - 1) >> BKT_SHIFT;            // 391
    const int npb  = (e + 256 * P1_EPT - 1) / (256 * P1_EPT);    // 391

    hipMemsetAsync(gcur, 0, 512 * sizeof(int), stream);

    // partition (CSR coarse pass) runs concurrently with gemm1 (independent)
    part_gemm1<<<npb + 512, 256, 0, stream>>>(src, dst, e, gcur, part, nbkt, npb,
                                              features, W1, al1, ar1, h16, el, er, n);
    // fine sort (includes its own bbase scan; cnt_scan kernel removed)
    finesort3<<<nbkt, 256, 0, stream>>>(part, gcur, row_off, csr_src, n, e, nbkt);

    // layer 1 aggregate
    agg_kernel<__half><<<4096, 256, 0, stream>>>(row_off, csr_src, h16, el, er, b1, hr, n, 1);

    // layer 2
    gemm_mfma_kernel<2, __half><<<512, 256, 0, stream>>>(hr, W2, al2, ar2, h16, el, er, n);
    agg_kernel<float><<<4096, 256, 0, stream>>>(row_off, csr_src, h16, el, er, b2, out, n, 0);
}